// Round 11
// baseline (53.414 us; speedup 1.0000x reference)
//
#include <hip/hip_runtime.h>

// BipolarMorphological2D SMorph:
//   out[b,o,s] = exp(sm(p1,k1)) - exp(sm(p1,k2)) - exp(sm(p2,k1)) + exp(sm(p2,k2)) + bias[o]
// with sm = sum(z*e^z)/sum(e^z), z = log(max(+/-x,0.1)) + kf[p,o].
// Factorization: e^z = m * e^kf ; z*e^z = (m*lm)*e^kf + m*(kf*e^kf)
// -> fp32 pk-FMA reductions over P=288, no transcendentals in the hot loop.
//
// R11: the ~28-31us floor of R4/R8/R10 is B L2->CU traffic: 276 MB at an
// implied ~16 B/cyc/CU per-CU L2 stream bandwidth (consistent across all
// three, TLP-invariant). Fix = spatial B reuse: block = 16 waves covering 16
// positions of one output row (grid 2x30x4 = 240 blocks) -> B L2 traffic
// 69 MB, staged once/block/phase into LDS (32 KB dbuf, issue-early/write-late
// so the stream hides under compute, ONE barrier per phase). A is read via
// wave-uniform VMEM loads (laundered "+v", L1-resident 27 KB window) - not
// s_load, not competing with B. VALU floor 11.5us; B-stage 2K cyc/phase
// hidden under 3K cyc compute.

typedef float v2f __attribute__((ext_vector_type(2)));

#define BB   4
#define CC   32
#define HH   32
#define WW   32
#define OO   64
#define HO   30
#define WO   30
#define NSP  (HO*WO)   // 900

// ---- prep: A[b,h,w,c] = (mp, mn, mp*log mp, mn*log mn)
//            Bm[ij,c,o] = (e^k1, k1*e^k1, e^k2, k2*e^k2)
__global__ __launch_bounds__(256) void smorph_prep(
    const float* __restrict__ x, const float* __restrict__ k1,
    const float* __restrict__ k2, float4* __restrict__ A, float4* __restrict__ Bm)
{
    int t = blockIdx.x * 256 + threadIdx.x;
    if (t < BB*CC*HH*WW) {
        float v = x[t];
        int b = t >> 15, c = (t >> 10) & 31, h = (t >> 5) & 31, w = t & 31;
        float mp = fmaxf(v, 0.1f), mn = fmaxf(-v, 0.1f);
        A[((b*HH + h)*WW + w)*CC + c] =
            make_float4(mp, mn, mp*logf(mp), mn*logf(mn));
    }
    if (t < 9*CC*OO) {
        float a = k1[t], bb = k2[t];
        float e1 = expf(a), e2 = expf(bb);
        Bm[t] = make_float4(e1, a*e1, e2, bb*e2);
    }
}

// Pin pointer in VGPRs: uniform loads stay on VMEM (not scalarized to s_load).
__device__ __forceinline__ const float4* as_vgpr(const float4* p) {
    asm("" : "+v"(p));
    return p;
}

// grid (2, 30, 4): x = 16-wide wo-tile, y = ho, z = b. 16 waves = 4 sg x 4 kq.
__global__ __launch_bounds__(1024, 4) void smorph_main(
    const float4* __restrict__ A, const float4* __restrict__ Bm,
    const float* __restrict__ bias, float* __restrict__ out)
{
    __shared__ __align__(16) float4 Bbuf[2][CC*OO];   // 64 KB B double-buffer
    v2f* ldsr = (v2f*)&Bbuf[0][0];                    // combine scratch view

    const int tid = threadIdx.x;
    const int o   = tid & 63;
    const int w   = tid >> 6;                          // wave 0..15
    const int sg  = w & 3;                             // spatial group
    const int kq  = __builtin_amdgcn_readfirstlane(w >> 2);  // c-range [8kq,8kq+8)
    const int ho  = blockIdx.y;
    const int b   = blockIdx.z;
    const int w0  = blockIdx.x*16 + sg*4;              // first wo of this wave

    const float4* Af = as_vgpr(A);

    v2f P1d[4] = {}, P1n[4] = {}, P2d[4] = {}, P2n[4] = {};

    // prologue: stage slice ij=0 into buf 0
    Bbuf[0][tid]        = Bm[tid];
    Bbuf[0][tid + 1024] = Bm[tid + 1024];
    __syncthreads();

    int buf = 0;
#pragma unroll
    for (int ij = 0; ij < 9; ++ij) {
        const int i = ij/3, j = ij - 3*(ij/3);

        float4 s0, s1;                 // issue-early loads of next B slice
        if (ij < 8) {
            const float4* src = Bm + (ij+1)*(CC*OO);
            s0 = src[tid]; s1 = src[tid + 1024];
        }

        const int arow = ((b*HH + ho + i)*WW)*CC + kq*8;   // uniform
        int acol[4];
#pragma unroll
        for (int t = 0; t < 4; ++t) {
            int wc = w0 + j + t; if (wc > WW-1) wc = WW-1;  // clamp (tail masked)
            acol[t] = wc * CC;
        }

#pragma unroll
        for (int ch = 0; ch < 4; ++ch) {                   // c-pairs of the 8-c range
            const int c0 = kq*8 + ch*2;
            float4 Bv0 = Bbuf[buf][(c0+0)*OO + o];         // ds_read_b128, conflict-free
            float4 Bv1 = Bbuf[buf][(c0+1)*OO + o];
            float4 Av[4][2];
#pragma unroll
            for (int t = 0; t < 4; ++t) {
                Av[t][0] = Af[arow + acol[t] + ch*2 + 0];  // uniform VMEM 16B
                Av[t][1] = Af[arow + acol[t] + ch*2 + 1];
            }
#pragma unroll
            for (int t = 0; t < 4; ++t) {
#pragma unroll
                for (int c = 0; c < 2; ++c) {
                    float4 Avv = Av[t][c];
                    float4 Bv  = c ? Bv1 : Bv0;
                    v2f a1 = {Avv.x, Avv.y};               // (mp, mn)
                    v2f a2 = {Avv.z, Avv.w};               // (mp*lmp, mn*lmn)
                    v2f be1 = {Bv.x, Bv.x}, bk1 = {Bv.y, Bv.y};
                    v2f be2 = {Bv.z, Bv.z}, bk2 = {Bv.w, Bv.w};
                    P1d[t] += a1 * be1;
                    P1n[t] += a2 * be1;
                    P1n[t] += a1 * bk1;
                    P2d[t] += a1 * be2;
                    P2n[t] += a2 * be2;
                    P2n[t] += a1 * bk2;
                }
            }
        }

        if (ij < 8) {                  // write-late: staging loads arrived long ago
            Bbuf[buf^1][tid]        = s0;
            Bbuf[buf^1][tid + 1024] = s1;
        }
        __syncthreads();               // one barrier per phase
        buf ^= 1;
    }

    // ---- combine kq partials (4-way, 2-level tree) in the B-buffer region
    if (kq >= 2) {
        v2f* dst = ldsr + ((kq - 2)*4 + sg)*1024 + o;
#pragma unroll
        for (int t = 0; t < 4; ++t) {
            dst[(t*4+0)*64] = P1d[t];
            dst[(t*4+1)*64] = P1n[t];
            dst[(t*4+2)*64] = P2d[t];
            dst[(t*4+3)*64] = P2n[t];
        }
    }
    __syncthreads();
    if (kq < 2) {
        const v2f* srcp = ldsr + (kq*4 + sg)*1024 + o;
#pragma unroll
        for (int t = 0; t < 4; ++t) {
            P1d[t] += srcp[(t*4+0)*64];
            P1n[t] += srcp[(t*4+1)*64];
            P2d[t] += srcp[(t*4+2)*64];
            P2n[t] += srcp[(t*4+3)*64];
        }
    }
    __syncthreads();
    if (kq == 1) {
        v2f* dst = ldsr + sg*1024 + o;
#pragma unroll
        for (int t = 0; t < 4; ++t) {
            dst[(t*4+0)*64] = P1d[t];
            dst[(t*4+1)*64] = P1n[t];
            dst[(t*4+2)*64] = P2d[t];
            dst[(t*4+3)*64] = P2n[t];
        }
    }
    __syncthreads();
    if (kq == 0) {
        const v2f* srcp = ldsr + sg*1024 + o;
        const float bo = bias[o];
#pragma unroll
        for (int t = 0; t < 4; ++t) {
            v2f d1 = P1d[t] + srcp[(t*4+0)*64];
            v2f n1 = P1n[t] + srcp[(t*4+1)*64];
            v2f d2 = P2d[t] + srcp[(t*4+2)*64];
            v2f n2 = P2n[t] + srcp[(t*4+3)*64];
            int wo = w0 + t;
            if (wo < WO) {
                float r = expf(n1.x/d1.x) - expf(n2.x/d2.x)
                        - expf(n1.y/d1.y) + expf(n2.y/d2.y) + bo;
                out[(size_t)(b*OO + o)*NSP + ho*WO + wo] = r;
            }
        }
    }
}

extern "C" void kernel_launch(void* const* d_in, const int* in_sizes, int n_in,
                              void* d_out, int out_size, void* d_ws, size_t ws_size,
                              hipStream_t stream) {
    const float* x    = (const float*)d_in[0];
    const float* k1   = (const float*)d_in[1];
    const float* k2   = (const float*)d_in[2];
    const float* bias = (const float*)d_in[3];

    float4* A  = (float4*)d_ws;                                   // 2 MB
    float4* Bm = (float4*)((char*)d_ws + (size_t)BB*HH*WW*CC*16); // 294 KB
    float*  out = (float*)d_out;

    hipLaunchKernelGGL(smorph_prep, dim3((BB*CC*HH*WW + 255)/256), dim3(256), 0, stream,
                       x, k1, k2, A, Bm);

    hipLaunchKernelGGL(smorph_main, dim3(2, HO, BB), dim3(1024), 0, stream,
                       A, Bm, bias, out);
}

// Round 12
// 30.466 us; speedup vs baseline: 1.7532x; 1.7532x over previous
//
#include <hip/hip_runtime.h>
#include <math.h>

// BipolarMorphological2D SMorph as a bf16 MFMA GEMM (R12).
//   out = exp(n1/d1)|pos - exp(n2/d2)|pos - exp(n1/d1)|neg + exp(n2/d2)|neg + bias
// delta-form: e^kf = 1 + delta, |delta|<=0.09 -> bf16(delta) has ~2e-4 abs err.
//   d = S_m + SUM m*delta ; n = S_mlm + SUM(mlm*delta + m*kappa), kappa = kf*e^kf
// S_m, S_mlm computed in fp32 by a box-sum kernel; the SUMs are one GEMM:
//   M = 7200 rows (s*2+sign interleaved), N = 256 (o*4+tbl), K = 576 (p*2+val)
//   A[row][k] = bf16 m or mlm of pixel(s + window(kh,kw), sign, c)  (gathered)
//   B[k][n]: tbl0: delta1/0, tbl1: kappa1/delta1, tbl2: delta2/0, tbl3: kappa2/delta2
// Wave tile 32Mx64N, full K, frags gathered per-lane with imm offsets (no LDS,
// no barriers in the loop). Epilogue: acc -> LDS transpose -> exp/div -> store.

typedef float  f32x4 __attribute__((ext_vector_type(4)));
typedef short  s16x8 __attribute__((ext_vector_type(8)));

#define BB   4
#define CC   32
#define HH   32
#define WW   32
#define OO   64
#define HO   30
#define WO   30
#define NSP  900
#define MS   3600
#define KDIM 576
#define NDIM 256

__device__ __forceinline__ unsigned short f2bf(float f) {
    unsigned u = __float_as_uint(f);
    return (unsigned short)((u + 0x7FFFu + ((u >> 16) & 1u)) >> 16);
}

// ---- prep: pixf[b,h,w,c] = (mp, mp*lmp, mn, mn*lmn) fp32 (for rowsum)
//            pixb[(pix*2+sign)*32+c] = packed bf16 (m | mlm<<16)
//            bt[n*576+k] = bf16 B table (delta/kappa form)
__global__ __launch_bounds__(256) void smorph_prep(
    const float* __restrict__ x, const float* __restrict__ k1,
    const float* __restrict__ k2, float4* __restrict__ pixf,
    unsigned* __restrict__ pixb, unsigned short* __restrict__ bt)
{
    int t = blockIdx.x * 256 + threadIdx.x;
    if (t < BB*CC*HH*WW) {
        float v = x[t];
        int b = t >> 15, c = (t >> 10) & 31, h = (t >> 5) & 31, w = t & 31;
        float mp = fmaxf(v, 0.1f), mn = fmaxf(-v, 0.1f);
        float lp = mp * logf(mp), ln_ = mn * logf(mn);
        int pix = (b*HH + h)*WW + w;
        pixf[(size_t)pix*CC + c] = make_float4(mp, lp, mn, ln_);
        pixb[(size_t)(pix*2 + 0)*CC + c] = (unsigned)f2bf(mp) | ((unsigned)f2bf(lp)  << 16);
        pixb[(size_t)(pix*2 + 1)*CC + c] = (unsigned)f2bf(mn) | ((unsigned)f2bf(ln_) << 16);
    }
    if (t < 9*CC*OO) {
        int o = t & 63, p = t >> 6;          // p = (kh*3+kw)*32 + c ; k1 flat = p*64+o
        float a = k1[t], b2 = k2[t];
        float d1 = expm1f(a),  q1 = a * expf(a);
        float d2 = expm1f(b2), q2 = b2 * expf(b2);
        int kb = p*2;
        size_t r0 = (size_t)(o*4+0)*KDIM + kb;
        size_t r1 = (size_t)(o*4+1)*KDIM + kb;
        size_t r2 = (size_t)(o*4+2)*KDIM + kb;
        size_t r3 = (size_t)(o*4+3)*KDIM + kb;
        bt[r0] = f2bf(d1); bt[r0+1] = 0;
        bt[r1] = f2bf(q1); bt[r1+1] = f2bf(d1);
        bt[r2] = f2bf(d2); bt[r2+1] = 0;
        bt[r3] = f2bf(q2); bt[r3+1] = f2bf(d2);
    }
}

// ---- rowsum: rs[s] = (S_m pos, S_mlm pos, S_m neg, S_mlm neg) fp32, 3x3x32 window
__global__ __launch_bounds__(128) void smorph_rowsum(
    const float4* __restrict__ pixf, float4* __restrict__ rs)
{
    __shared__ float4 sums[3*32];
    int ho = blockIdx.x, b = blockIdx.y, tid = threadIdx.x;
    if (tid < 96) {
        int hr = tid >> 5, w = tid & 31;
        const float4* p = pixf + (size_t)((b*HH + ho + hr)*WW + w)*CC;
        float4 s = make_float4(0,0,0,0);
        for (int c = 0; c < CC; ++c) {
            float4 v = p[c];
            s.x += v.x; s.y += v.y; s.z += v.z; s.w += v.w;
        }
        sums[tid] = s;
    }
    __syncthreads();
    if (tid < WO) {
        float4 s = make_float4(0,0,0,0);
#pragma unroll
        for (int kh = 0; kh < 3; ++kh)
#pragma unroll
            for (int kw = 0; kw < 3; ++kw) {
                float4 v = sums[kh*32 + tid + kw];
                s.x += v.x; s.y += v.y; s.z += v.z; s.w += v.w;
            }
        rs[b*NSP + ho*WO + tid] = s;
    }
}

// ---- GEMM + epilogue: 450 blocks x 128 thr (2 waves). Wave: 32M x 64N, K=576.
__global__ __launch_bounds__(128, 1) void smorph_gemm(
    const unsigned* __restrict__ pixb, const unsigned short* __restrict__ bt,
    const float4* __restrict__ rs, const float* __restrict__ bias,
    float* __restrict__ out)
{
    __shared__ __align__(16) float lds[2][32*66];

    const int tid = threadIdx.x;
    const int l   = tid & 63;
    const int w   = tid >> 6;                  // wave 0..1
    const int bm  = blockIdx.x % 225;          // M-block: rows 32bm..32bm+31
    const int nh  = blockIdx.x / 225;          // N-half
    const int N0  = nh*128 + w*64;

    const int lr = l & 15;                     // frag row/col
    const int lg = l >> 4;                     // k-group

    // A lane byte-offsets (row: s = bm*16 + mi*8 + lr/2, sign = lr&1)
    unsigned offA[2];
    const int sign = lr & 1;
#pragma unroll
    for (int mi = 0; mi < 2; ++mi) {
        int s   = bm*16 + mi*8 + (lr >> 1);
        int b   = s / NSP, rem = s - b*NSP;
        int ho  = rem / WO, wo = rem - ho*WO;
        int pix = (b*HH + ho)*WW + wo;
        offA[mi] = (unsigned)(pix*256 + sign*128 + lg*16);
    }
    // B lane byte-offsets (col n = N0 + ni*16 + lr)
    unsigned offB[4];
#pragma unroll
    for (int ni = 0; ni < 4; ++ni)
        offB[ni] = (unsigned)(((N0 + ni*16 + lr)*KDIM + lg*8) * 2);

    const char* pa = (const char*)pixb;
    const char* pb = (const char*)bt;

    f32x4 acc[2][4] = {};

#pragma unroll
    for (int step = 0; step < 18; ++step) {
        const int khkw  = step >> 1;
        const int kh    = khkw / 3, kw = khkw - 3*(khkw/3);
        const int khalf = step & 1;
        const unsigned immA = (unsigned)(kh*8192 + kw*256 + khalf*64);
        const unsigned immB = (unsigned)(step*64);

        s16x8 a0 = *(const s16x8*)(pa + (offA[0] + immA));
        s16x8 a1 = *(const s16x8*)(pa + (offA[1] + immA));
        s16x8 b0 = *(const s16x8*)(pb + (offB[0] + immB));
        s16x8 b1 = *(const s16x8*)(pb + (offB[1] + immB));
        s16x8 b2 = *(const s16x8*)(pb + (offB[2] + immB));
        s16x8 b3 = *(const s16x8*)(pb + (offB[3] + immB));

        acc[0][0] = __builtin_amdgcn_mfma_f32_16x16x32_bf16(a0, b0, acc[0][0], 0, 0, 0);
        acc[0][1] = __builtin_amdgcn_mfma_f32_16x16x32_bf16(a0, b1, acc[0][1], 0, 0, 0);
        acc[0][2] = __builtin_amdgcn_mfma_f32_16x16x32_bf16(a0, b2, acc[0][2], 0, 0, 0);
        acc[0][3] = __builtin_amdgcn_mfma_f32_16x16x32_bf16(a0, b3, acc[0][3], 0, 0, 0);
        acc[1][0] = __builtin_amdgcn_mfma_f32_16x16x32_bf16(a1, b0, acc[1][0], 0, 0, 0);
        acc[1][1] = __builtin_amdgcn_mfma_f32_16x16x32_bf16(a1, b1, acc[1][1], 0, 0, 0);
        acc[1][2] = __builtin_amdgcn_mfma_f32_16x16x32_bf16(a1, b2, acc[1][2], 0, 0, 0);
        acc[1][3] = __builtin_amdgcn_mfma_f32_16x16x32_bf16(a1, b3, acc[1][3], 0, 0, 0);
    }

    // ---- epilogue: acc -> LDS [row 0..31][col 0..63], pitch 66
    {
        float* L = &lds[w][0];
        const int wrbase = lg*4*66 + lr;       // row = mi*16 + lg*4 + r, col = ni*16 + lr
#pragma unroll
        for (int mi = 0; mi < 2; ++mi)
#pragma unroll
            for (int ni = 0; ni < 4; ++ni)
#pragma unroll
                for (int r = 0; r < 4; ++r)
                    L[wrbase + (mi*16 + r)*66 + ni*16] = acc[mi][ni][r];
    }
    __syncthreads();

    {
        const int sl = lr;                     // 0..15 : local s
        const int oq = lg;                     // 0..3  : o-quarter
        const int s  = bm*16 + sl;
        const int b  = s / NSP;
        const int r900 = s - b*NSP;
        const float4 S = rs[s];                // (Smp, Smlmp, Smn, Smlmn)
        const float* Lw = &lds[w][0];
#pragma unroll
        for (int oi = 0; oi < 4; ++oi) {
            int ol = oq*4 + oi;                // local o 0..15
            int o  = (N0 >> 2) + ol;
            float4 v0 = *(const float4*)&Lw[(2*sl + 0)*66 + ol*4];  // pos: d1,n1,d2,n2
            float4 v1 = *(const float4*)&Lw[(2*sl + 1)*66 + ol*4];  // neg
            float d1p = S.x + v0.x, n1p = S.y + v0.y;
            float d2p = S.x + v0.z, n2p = S.y + v0.w;
            float d1n = S.z + v1.x, n1n = S.w + v1.y;
            float d2n = S.z + v1.z, n2n = S.w + v1.w;
            float P = __expf(n1p/d1p) - __expf(n2p/d2p)
                    - __expf(n1n/d1n) + __expf(n2n/d2n);
            out[((size_t)(b*OO + o))*NSP + r900] = P + bias[o];
        }
    }
}

extern "C" void kernel_launch(void* const* d_in, const int* in_sizes, int n_in,
                              void* d_out, int out_size, void* d_ws, size_t ws_size,
                              hipStream_t stream) {
    const float* x    = (const float*)d_in[0];
    const float* k1   = (const float*)d_in[1];
    const float* k2   = (const float*)d_in[2];
    const float* bias = (const float*)d_in[3];

    char* ws = (char*)d_ws;
    float4*         pixf = (float4*)(ws);                    // 2 MB
    unsigned*       pixb = (unsigned*)(ws + 0x200000);       // 1 MB
    unsigned short* bt   = (unsigned short*)(ws + 0x300000); // 288 KB
    float4*         rsum = (float4*)(ws + 0x350000);         // 57.6 KB
    float*          out  = (float*)d_out;

    hipLaunchKernelGGL(smorph_prep, dim3(512), dim3(256), 0, stream,
                       x, k1, k2, pixf, pixb, bt);
    hipLaunchKernelGGL(smorph_rowsum, dim3(HO, BB), dim3(128), 0, stream,
                       pixf, rsum);
    hipLaunchKernelGGL(smorph_gemm, dim3(450), dim3(128), 0, stream,
                       pixb, bt, rsum, bias, out);
}

// Round 13
// 21.497 us; speedup vs baseline: 2.4847x; 1.4172x over previous
//
#include <hip/hip_runtime.h>
#include <math.h>

// BipolarMorphological2D SMorph as a bf16 MFMA GEMM (R13).
// delta-form: e^kf = 1 + delta -> d = S_m + GEMM(m,delta); n = S_mlm + GEMM(..)
//   M = 7200 (s*2+sign), N = 256 (o*4+tbl), K = 576 (c*2+{m,mlm} per 3x3 pos)
// R13 vs R12: (1) A and B PRE-PACKED in exact MFMA fragment order -> every
// GEMM load is lane-linear (1KB coalesced per wave-instr); the gather cost
// moves to the 8192-wave prep kernel. (2) rowsum kernel eliminated: prep
// computes per-pixel c-sums via shfl_xor (pixs, 64KB); gemm sums 9 broadcast
// float4 per lane into registers. 2 kernels total.

typedef float  f32x4 __attribute__((ext_vector_type(4)));
typedef short  s16x8 __attribute__((ext_vector_type(8)));

#define BB   4
#define CC   32
#define HH   32
#define WW   32
#define OO   64
#define HO   30
#define WO   30
#define NSP  900
#define KDIM 576

#define T1   131072            // branch1: pixel sums (512 blocks)
#define T2   (T1 + 518400)     // branch2: A3 pack   (2025 blocks)
#define T3   (T2 + 18432)      // branch3: B pack    (72 blocks)

__device__ __forceinline__ unsigned short f2bf(float f) {
    unsigned u = __float_as_uint(f);
    return (unsigned short)((u + 0x7FFFu + ((u >> 16) & 1u)) >> 16);
}

// ---- prep: pixs[pix] = fp32 c-sums (Smp, Smlmp, Smn, Smlmn) per pixel
//            A3: bf16 A in MFMA-frag order: [mtile(225)][step(18)][mi(2)][lane(64)] x 16B
//            bt: bf16 B in MFMA-frag order: [ng(16)][step(18)][lane(64)] x 16B
__global__ __launch_bounds__(256) void smorph_prep(
    const float* __restrict__ x, const float* __restrict__ k1,
    const float* __restrict__ k2, float4* __restrict__ pixs,
    uint4* __restrict__ A3, unsigned short* __restrict__ bt)
{
    const int t = blockIdx.x * 256 + threadIdx.x;

    if (t < T1) {
        // t = pix*32 + c  (c innermost -> shfl reduction over c)
        const int pix = t >> 5, c = t & 31;
        const int b = pix >> 10, h = (pix >> 5) & 31, w = pix & 31;
        float v = x[b*32768 + c*1024 + h*32 + w];      // stride-4KB (L2, high TLP)
        float mp = fmaxf(v, 0.1f), mn = fmaxf(-v, 0.1f);
        float lp = mp * logf(mp), ln_ = mn * logf(mn);
        float s0 = mp, s1 = lp, s2 = mn, s3 = ln_;
#pragma unroll
        for (int m = 16; m >= 1; m >>= 1) {
            s0 += __shfl_xor(s0, m); s1 += __shfl_xor(s1, m);
            s2 += __shfl_xor(s2, m); s3 += __shfl_xor(s3, m);
        }
        if (c == 0) pixs[pix] = make_float4(s0, s1, s2, s3);
    } else if (t < T2) {
        // A3 pack: u -> (mtile, step, mi, lane); 4 channels per thread
        const int u   = t - T1;
        const int mt  = u / 2304, rem = u - mt*2304;
        const int st  = rem >> 7, rem2 = rem & 127;
        const int mi  = rem2 >> 6, l = rem2 & 63;
        const int lr  = l & 15, lg = l >> 4;
        const int s   = mt*16 + mi*8 + (lr >> 1);
        const int sign = lr & 1;
        const int pos = st >> 1, khalf = st & 1;
        const int kh  = pos / 3, kw = pos - 3*(pos/3);
        const int b   = s / NSP, r = s - b*NSP;
        const int ho  = r / WO,  wo = r - WO*(r/WO);
        const int h   = ho + kh, w = wo + kw;
        const int c0  = khalf*16 + lg*4;
        const int base = b*32768 + h*32 + w;
        unsigned pk[4];
#pragma unroll
        for (int q = 0; q < 4; ++q) {
            float v = x[base + (c0 + q)*1024];
            float m = sign ? fmaxf(-v, 0.1f) : fmaxf(v, 0.1f);
            pk[q] = (unsigned)f2bf(m) | ((unsigned)f2bf(m * logf(m)) << 16);
        }
        A3[u] = make_uint4(pk[0], pk[1], pk[2], pk[3]);
    } else if (t < T3) {
        // B pack: u -> (o, p); 4 tables x 2 k-slots
        const int u3 = t - T2;
        const int o = u3 & 63, p = u3 >> 6;
        const float a = k1[u3], b2 = k2[u3];
        const float d1 = expm1f(a),  q1 = a  * expf(a);
        const float d2 = expm1f(b2), q2 = b2 * expf(b2);
        const float vals[4][2] = {{d1, 0.f}, {q1, d1}, {d2, 0.f}, {q2, d2}};
#pragma unroll
        for (int tbl = 0; tbl < 4; ++tbl) {
            const int n = o*4 + tbl;
#pragma unroll
            for (int ks = 0; ks < 2; ++ks) {
                const int k    = 2*p + ks;
                const int st   = k >> 5, k32 = k & 31;
                const int lane = (n & 15) + ((k32 >> 3) << 4);
                bt[((n >> 4)*18 + st)*512 + lane*8 + (k32 & 7)] = f2bf(vals[tbl][ks]);
            }
        }
    }
}

// ---- GEMM + epilogue: 450 blocks x 128 thr (2 waves). Wave: 32M x 64N, K=576.
__global__ __launch_bounds__(128) void smorph_gemm(
    const uint4* __restrict__ A3, const unsigned short* __restrict__ bt,
    const float4* __restrict__ pixs, const float* __restrict__ bias,
    float* __restrict__ out)
{
    __shared__ __align__(16) float lds[2][32*66];

    const int tid = threadIdx.x;
    const int l   = tid & 63;
    const int w   = tid >> 6;                  // wave 0..1
    const int bm  = blockIdx.x >> 1;           // M-tile (16 s, 32 rows)
    const int nh  = blockIdx.x & 1;            // N-half
    const int N0  = nh*128 + w*64;
    const int ng0 = N0 >> 4;

    const int lr = l & 15;
    const int lg = l >> 4;

    // ---- per-lane fp32 window sums (issued first; used only in epilogue)
    float4 S;
    {
        const int s  = bm*16 + lr;
        const int b  = s / NSP, r = s - b*NSP;
        const int ho = r / WO,  wo = r - WO*(r/WO);
        const float4* P = pixs + (b*1024 + ho*32 + wo);
        float4 acc = make_float4(0,0,0,0);
#pragma unroll
        for (int kh = 0; kh < 3; ++kh)
#pragma unroll
            for (int kw = 0; kw < 3; ++kw) {
                float4 v = P[kh*32 + kw];
                acc.x += v.x; acc.y += v.y; acc.z += v.z; acc.w += v.w;
            }
        S = acc;
    }

    const uint4* Ap = A3 + ((size_t)bm*18)*128 + l;     // + (step*2+mi)*64
    const char*  pb = (const char*)bt;

    f32x4 acc[2][4] = {};

#pragma unroll
    for (int step = 0; step < 18; ++step) {
        s16x8 a0 = *(const s16x8*)(Ap + (step*2 + 0)*64);
        s16x8 a1 = *(const s16x8*)(Ap + (step*2 + 1)*64);
        s16x8 b0 = *(const s16x8*)(pb + (((ng0+0)*18 + step)*64 + l)*16);
        s16x8 b1 = *(const s16x8*)(pb + (((ng0+1)*18 + step)*64 + l)*16);
        s16x8 b2 = *(const s16x8*)(pb + (((ng0+2)*18 + step)*64 + l)*16);
        s16x8 b3 = *(const s16x8*)(pb + (((ng0+3)*18 + step)*64 + l)*16);

        acc[0][0] = __builtin_amdgcn_mfma_f32_16x16x32_bf16(a0, b0, acc[0][0], 0, 0, 0);
        acc[0][1] = __builtin_amdgcn_mfma_f32_16x16x32_bf16(a0, b1, acc[0][1], 0, 0, 0);
        acc[0][2] = __builtin_amdgcn_mfma_f32_16x16x32_bf16(a0, b2, acc[0][2], 0, 0, 0);
        acc[0][3] = __builtin_amdgcn_mfma_f32_16x16x32_bf16(a0, b3, acc[0][3], 0, 0, 0);
        acc[1][0] = __builtin_amdgcn_mfma_f32_16x16x32_bf16(a1, b0, acc[1][0], 0, 0, 0);
        acc[1][1] = __builtin_amdgcn_mfma_f32_16x16x32_bf16(a1, b1, acc[1][1], 0, 0, 0);
        acc[1][2] = __builtin_amdgcn_mfma_f32_16x16x32_bf16(a1, b2, acc[1][2], 0, 0, 0);
        acc[1][3] = __builtin_amdgcn_mfma_f32_16x16x32_bf16(a1, b3, acc[1][3], 0, 0, 0);
    }

    // ---- epilogue: acc -> LDS [row 0..31][col 0..63], pitch 66
    {
        float* L = &lds[w][0];
        const int wrbase = lg*4*66 + lr;
#pragma unroll
        for (int mi = 0; mi < 2; ++mi)
#pragma unroll
            for (int ni = 0; ni < 4; ++ni)
#pragma unroll
                for (int r = 0; r < 4; ++r)
                    L[wrbase + (mi*16 + r)*66 + ni*16] = acc[mi][ni][r];
    }
    __syncthreads();

    {
        const int sl = lr;                      // local s (S already per-lane!)
        const int oq = lg;                      // o-quarter
        const int s  = bm*16 + sl;
        const int b  = s / NSP;
        const int r900 = s - b*NSP;
        const float* Lw = &lds[w][0];
#pragma unroll
        for (int oi = 0; oi < 4; ++oi) {
            int ol = oq*4 + oi;
            int o  = (N0 >> 2) + ol;
            float4 v0 = *(const float4*)&Lw[(2*sl + 0)*66 + ol*4];  // pos: d1,n1,d2,n2
            float4 v1 = *(const float4*)&Lw[(2*sl + 1)*66 + ol*4];  // neg
            float d1p = S.x + v0.x, n1p = S.y + v0.y;
            float d2p = S.x + v0.z, n2p = S.y + v0.w;
            float d1n = S.z + v1.x, n1n = S.w + v1.y;
            float d2n = S.z + v1.z, n2n = S.w + v1.w;
            float P = __expf(n1p/d1p) - __expf(n2p/d2p)
                    - __expf(n1n/d1n) + __expf(n2n/d2n);
            out[((size_t)(b*OO + o))*NSP + r900] = P + bias[o];
        }
    }
}

extern "C" void kernel_launch(void* const* d_in, const int* in_sizes, int n_in,
                              void* d_out, int out_size, void* d_ws, size_t ws_size,
                              hipStream_t stream) {
    const float* x    = (const float*)d_in[0];
    const float* k1   = (const float*)d_in[1];
    const float* k2   = (const float*)d_in[2];
    const float* bias = (const float*)d_in[3];

    char* ws = (char*)d_ws;
    float4*         pixs = (float4*)(ws);                 // 64 KB
    uint4*          A3   = (uint4*)(ws + 0x10000);        // 8,294,400 B
    unsigned short* bt   = (unsigned short*)(ws + 0x7F9000); // 294,912 B
    float*          out  = (float*)d_out;

    hipLaunchKernelGGL(smorph_prep, dim3(T3/256), dim3(256), 0, stream,
                       x, k1, k2, pixs, A3, bt);
    hipLaunchKernelGGL(smorph_gemm, dim3(450), dim3(128), 0, stream,
                       A3, bt, pixs, bias, out);
}